// Round 2
// baseline (135.686 us; speedup 1.0000x reference)
//
#include <hip/hip_runtime.h>

#define NTOK 8192
#define EMB 1024
#define KNOISE 10
#define KP1 11
#define M_ITEMS (NTOK * KP1)        // 90112
#define NVOCAB 50257
#define BSHIFT 6
#define NB ((NVOCAB + 63) >> 6)     // 786 buckets of 64 rows (256 KB weight each)
#define NORM_TERM 9.0f

// ws byte offsets (total ~1.1 MB, ws is much larger)
#define OFF_HIST   0
#define OFF_CURSOR 4096
#define OFF_ROW    8192
#define OFF_M      (OFF_ROW + M_ITEMS * 4)
#define OFF_LOGIT  (OFF_M + M_ITEMS * 4)
#define OFF_PART   (OFF_LOGIT + M_ITEMS * 4)

__device__ __forceinline__ int item_row(int m, const int* __restrict__ target,
                                        const int* __restrict__ ns) {
    const int n = (unsigned)m / KP1;
    const int j = m - n * KP1;
    return (j == 0) ? target[n] : ns[n * KNOISE + (j - 1)];
}

__global__ __launch_bounds__(1024) void zero_hist_kernel(int* __restrict__ hist) {
    if (threadIdx.x < NB) hist[threadIdx.x] = 0;
}

__global__ __launch_bounds__(256) void hist_kernel(
    const int* __restrict__ target, const int* __restrict__ ns,
    int* __restrict__ hist)
{
    const int m = blockIdx.x * 256 + threadIdx.x;
    const int row = item_row(m, target, ns);
    atomicAdd(&hist[row >> BSHIFT], 1);
}

__global__ __launch_bounds__(1024) void scan_kernel(
    const int* __restrict__ hist, int* __restrict__ cursor)
{
    __shared__ int s[1024];
    const int t = threadIdx.x;
    const int v = (t < NB) ? hist[t] : 0;
    s[t] = v;
    __syncthreads();
    #pragma unroll
    for (int off = 1; off < 1024; off <<= 1) {
        int u = (t >= off) ? s[t - off] : 0;
        __syncthreads();
        s[t] += u;
        __syncthreads();
    }
    if (t < NB) cursor[t] = s[t] - v;   // exclusive prefix
}

__global__ __launch_bounds__(256) void scatter_kernel(
    const int* __restrict__ target, const int* __restrict__ ns,
    int* __restrict__ cursor, int* __restrict__ sorted_row, int* __restrict__ sorted_m)
{
    const int m = blockIdx.x * 256 + threadIdx.x;
    const int row = item_row(m, target, ns);
    const int pos = atomicAdd(&cursor[row >> BSHIFT], 1);
    sorted_row[pos] = row;
    sorted_m[pos] = m;
}

// One wave per sorted gather item: dot(input[n], weight[row]) + bias[row]
__global__ __launch_bounds__(256) void dot_kernel(
    const float* __restrict__ input, const float* __restrict__ weight,
    const float* __restrict__ bias,
    const int* __restrict__ sorted_row, const int* __restrict__ sorted_m,
    float* __restrict__ logits)
{
    const int nblk = M_ITEMS / 4;               // 22528, divisible by 8
    const int bid = blockIdx.x;
    // XCD-chunked swizzle: each XCD gets a contiguous chunk of sorted items
    const int swz = (bid & 7) * (nblk >> 3) + (bid >> 3);
    const int item = swz * 4 + (threadIdx.x >> 6);
    const int lane = threadIdx.x & 63;

    const int row = sorted_row[item];
    const int m = sorted_m[item];
    const int n = (unsigned)m / KP1;

    const float4* wr = reinterpret_cast<const float4*>(weight + (size_t)row * EMB);
    const float4* xr = reinterpret_cast<const float4*>(input + (size_t)n * EMB);
    float acc = 0.f;
    #pragma unroll
    for (int j = 0; j < 4; ++j) {
        const float4 w4 = wr[lane + 64 * j];
        const float4 x4 = xr[lane + 64 * j];
        acc = fmaf(w4.x, x4.x, acc);
        acc = fmaf(w4.y, x4.y, acc);
        acc = fmaf(w4.z, x4.z, acc);
        acc = fmaf(w4.w, x4.w, acc);
    }
    #pragma unroll
    for (int off = 32; off > 0; off >>= 1)
        acc += __shfl_xor(acc, off, 64);
    if (lane == 0) logits[m] = acc + bias[row];
}

__global__ __launch_bounds__(256) void loss_kernel(
    const float* __restrict__ logits, const float* __restrict__ noise,
    const int* __restrict__ target, const int* __restrict__ ns,
    float* __restrict__ partials)
{
    const int n = blockIdx.x * 256 + threadIdx.x;
    const float* lg = logits + n * KP1;
    const int t = target[n];
    const float p0 = expf(lg[0] - NORM_TERM);
    const float kn0 = (float)KNOISE * noise[t];
    float loss = logf(p0 / (p0 + kn0));
    #pragma unroll
    for (int k = 0; k < KNOISE; ++k) {
        const int s = ns[n * KNOISE + k];
        const float pk = expf(lg[k + 1] - NORM_TERM);
        const float kn = (float)KNOISE * noise[s];
        loss += logf(kn / (pk + kn));
    }
    __shared__ float red[256];
    red[threadIdx.x] = loss;
    __syncthreads();
    #pragma unroll
    for (int off = 128; off > 0; off >>= 1) {
        if (threadIdx.x < off) red[threadIdx.x] += red[threadIdx.x + off];
        __syncthreads();
    }
    if (threadIdx.x == 0) partials[blockIdx.x] = red[0];
}

__global__ __launch_bounds__(64) void final_kernel(
    const float* __restrict__ partials, float* __restrict__ out)
{
    if (threadIdx.x == 0) {
        float s = 0.f;
        for (int i = 0; i < 32; ++i) s += partials[i];
        out[0] = -s / (float)NTOK;
    }
}

extern "C" void kernel_launch(void* const* d_in, const int* in_sizes, int n_in,
                              void* d_out, int out_size, void* d_ws, size_t ws_size,
                              hipStream_t stream) {
    const float* input  = (const float*)d_in[0];
    const float* weight = (const float*)d_in[1];
    const float* bias   = (const float*)d_in[2];
    const float* noise  = (const float*)d_in[3];
    const int* target   = (const int*)d_in[4];
    const int* ns       = (const int*)d_in[5];

    char* ws = (char*)d_ws;
    int* hist       = (int*)(ws + OFF_HIST);
    int* cursor     = (int*)(ws + OFF_CURSOR);
    int* sorted_row = (int*)(ws + OFF_ROW);
    int* sorted_m   = (int*)(ws + OFF_M);
    float* logits   = (float*)(ws + OFF_LOGIT);
    float* partials = (float*)(ws + OFF_PART);

    zero_hist_kernel<<<1, 1024, 0, stream>>>(hist);
    hist_kernel<<<M_ITEMS / 256, 256, 0, stream>>>(target, ns, hist);
    scan_kernel<<<1, 1024, 0, stream>>>(hist, cursor);
    scatter_kernel<<<M_ITEMS / 256, 256, 0, stream>>>(target, ns, cursor, sorted_row, sorted_m);
    dot_kernel<<<M_ITEMS / 4, 256, 0, stream>>>(input, weight, bias, sorted_row, sorted_m, logits);
    loss_kernel<<<NTOK / 256, 256, 0, stream>>>(logits, noise, target, ns, partials);
    final_kernel<<<1, 64, 0, stream>>>(partials, (float*)d_out);
}

// Round 3
// 82.219 us; speedup vs baseline: 1.6503x; 1.6503x over previous
//
#include <hip/hip_runtime.h>

#define N_TOK 8192
#define EMB 1024
#define KNOISE 10
#define KP1 11
#define NORM_TERM 9.0f

typedef float f4 __attribute__((ext_vector_type(4)));

__global__ __launch_bounds__(256) void nce_token_kernel(
    const float* __restrict__ input,
    const float* __restrict__ weight,
    const float* __restrict__ bias,
    const float* __restrict__ noise,
    const int* __restrict__ target,
    const int* __restrict__ ns,
    float* __restrict__ token_loss)
{
    __shared__ f4 s_in[EMB / 4];   // 4 KB input row
    __shared__ float s_dot[16];    // 11 used

    const int n = blockIdx.x;
    const int tid = threadIdx.x;
    const int wave = tid >> 6;
    const int lane = tid & 63;

    // Stage input row in LDS, nontemporal (used once; keep LLC for weight).
    const f4* inrow = reinterpret_cast<const f4*>(input + (size_t)n * EMB);
    s_in[tid] = __builtin_nontemporal_load(&inrow[tid]);
    __syncthreads();

    // Wave w owns k = w, w+4, w+8 (wave 3 has only k=3,7). Compute all its
    // dots simultaneously: 12 global loads in flight, LDS read reused 3x.
    int rows[3];
    #pragma unroll
    for (int i = 0; i < 3; ++i) {
        const int k = wave + 4 * i;
        rows[i] = (k < KP1) ? ((k == 0) ? target[n] : ns[n * KNOISE + (k - 1)]) : -1;
    }
    const f4* wr[3];
    #pragma unroll
    for (int i = 0; i < 3; ++i)
        wr[i] = reinterpret_cast<const f4*>(weight + (size_t)(rows[i] >= 0 ? rows[i] : 0) * EMB);

    float acc[3] = {0.f, 0.f, 0.f};
    #pragma unroll
    for (int j = 0; j < 4; ++j) {
        const f4 x4 = s_in[lane + 64 * j];
        #pragma unroll
        for (int i = 0; i < 3; ++i) {
            if (rows[i] >= 0) {   // wave-uniform branch
                const f4 w4 = wr[i][lane + 64 * j];
                acc[i] = fmaf(w4.x, x4.x, acc[i]);
                acc[i] = fmaf(w4.y, x4.y, acc[i]);
                acc[i] = fmaf(w4.z, x4.z, acc[i]);
                acc[i] = fmaf(w4.w, x4.w, acc[i]);
            }
        }
    }
    // Interleaved butterfly reduces (latencies of the 3 chains overlap).
    #pragma unroll
    for (int off = 32; off > 0; off >>= 1) {
        #pragma unroll
        for (int i = 0; i < 3; ++i)
            acc[i] += __shfl_xor(acc[i], off, 64);
    }
    if (lane == 0) {
        #pragma unroll
        for (int i = 0; i < 3; ++i)
            if (rows[i] >= 0) s_dot[wave + 4 * i] = acc[i] + bias[rows[i]];
    }
    __syncthreads();

    if (tid == 0) {
        const int t = target[n];
        const float p0 = expf(s_dot[0] - NORM_TERM);
        const float kn0 = (float)KNOISE * noise[t];
        float loss = logf(p0 / (p0 + kn0));
        #pragma unroll
        for (int k = 0; k < KNOISE; ++k) {
            const int s = ns[n * KNOISE + k];
            const float pk = expf(s_dot[k + 1] - NORM_TERM);
            const float kn = (float)KNOISE * noise[s];
            loss += logf(kn / (pk + kn));
        }
        __builtin_nontemporal_store(loss, &token_loss[n]);
    }
}

__global__ __launch_bounds__(256) void nce_reduce_kernel(
    const float* __restrict__ token_loss, float* __restrict__ out)
{
    __shared__ float s_part[4];
    float acc = 0.f;
    for (int i = threadIdx.x; i < N_TOK; i += 256)
        acc += __builtin_nontemporal_load(&token_loss[i]);
    #pragma unroll
    for (int off = 32; off > 0; off >>= 1)
        acc += __shfl_xor(acc, off, 64);
    const int wave = threadIdx.x >> 6;
    const int lane = threadIdx.x & 63;
    if (lane == 0) s_part[wave] = acc;
    __syncthreads();
    if (threadIdx.x == 0) {
        const float total = s_part[0] + s_part[1] + s_part[2] + s_part[3];
        out[0] = -total / (float)N_TOK;
    }
}

extern "C" void kernel_launch(void* const* d_in, const int* in_sizes, int n_in,
                              void* d_out, int out_size, void* d_ws, size_t ws_size,
                              hipStream_t stream) {
    const float* input  = (const float*)d_in[0];
    const float* weight = (const float*)d_in[1];
    const float* bias   = (const float*)d_in[2];
    const float* noise  = (const float*)d_in[3];
    const int* target   = (const int*)d_in[4];
    const int* ns       = (const int*)d_in[5];

    float* token_loss = (float*)d_ws;   // 32 KB scratch

    nce_token_kernel<<<N_TOK, 256, 0, stream>>>(
        input, weight, bias, noise, target, ns, token_loss);
    nce_reduce_kernel<<<1, 256, 0, stream>>>(token_loss, (float*)d_out);
}